// Round 8
// baseline (451.024 us; speedup 1.0000x reference)
//
#include <hip/hip_runtime.h>
#include <hip/hip_bf16.h>

#define GN 16384
#define GDIM 64

typedef __attribute__((ext_vector_type(8))) short bf16x8;
typedef __attribute__((ext_vector_type(4))) float f32x4;
typedef __attribute__((ext_vector_type(4))) unsigned short u16x4;

typedef __attribute__((address_space(1))) const void GASV;
typedef __attribute__((address_space(3))) void LASV;

__device__ __forceinline__ unsigned short f2bf(float x) {
    unsigned int u = __builtin_bit_cast(unsigned int, x);
    u += 0x7fffu + ((u >> 16) & 1u);          // round-to-nearest-even
    return (unsigned short)(u >> 16);
}

// compiler-visible float->bf16 cast; lowers to v_cvt_pk_bf16_f32 pairs (RNE)
__device__ __forceinline__ short f2bf_hw(float x) {
    __hip_bfloat16 b = __float2bfloat16(x);
    return (short)__builtin_bit_cast(unsigned short, b);
}

// ---------------- K1a: per-feature partial sums of h (256 blocks x 64 rows) ----
__global__ void bn_partial(const float* __restrict__ h, float* __restrict__ ps,
                           float* __restrict__ pq) {
    int b = blockIdx.x, t = threadIdx.x;
    int col = t & 63, wr = t >> 6;
    float s = 0.f, q = 0.f;
    int base = b * 64;
    for (int rep = 0; rep < 16; ++rep) {
        int row = base + wr + rep * 4;
        float v = h[row * GDIM + col];
        s += v; q += v * v;
    }
    __shared__ float ls[4][64], lq[4][64];
    ls[wr][col] = s; lq[wr][col] = q;
    __syncthreads();
    if (t < 64) {
        ps[b * 64 + t] = ls[0][t] + ls[1][t] + ls[2][t] + ls[3][t];
        pq[b * 64 + t] = lq[0][t] + lq[1][t] + lq[2][t] + lq[3][t];
    }
}

// ---------------- K1b: finalize BN stats, fold into W' and b' ------------------
__global__ void bn_finalize(const float* __restrict__ ps, const float* __restrict__ pq,
                            const float* __restrict__ W, const float* __restrict__ bvec,
                            const float* __restrict__ gamma, const float* __restrict__ beta,
                            float* __restrict__ Wp, float* __restrict__ bp) {
    int t = threadIdx.x;
    __shared__ float s_s[64], s_t2[64];
    if (t < 64) {
        float S = 0.f, Q = 0.f;
        for (int b = 0; b < 256; ++b) { S += ps[b * 64 + t]; Q += pq[b * 64 + t]; }
        float mean = S * (1.0f / 16384.0f);
        float var  = Q * (1.0f / 16384.0f) - mean * mean;
        float sc   = gamma[t] * rsqrtf(var + 1e-5f);
        s_s[t]  = sc;
        s_t2[t] = beta[t] - mean * sc;
    }
    __syncthreads();
    for (int k = 0; k < 16; ++k) {
        int idx = t + k * 256;
        Wp[idx] = s_s[idx & 63] * W[idx];
    }
    if (t < 64) {
        float acc = bvec[t];
        for (int c = 0; c < 64; ++c) acc += s_t2[c] * W[t * 64 + c];
        bp[t] = acc;
    }
}

// ---------------- K2: hp = h @ W'^T + b'   (1024 blocks x 16 rows) -------------
__global__ void linear_hp(const float* __restrict__ h, const float* __restrict__ Wp,
                          const float* __restrict__ bpr, float* __restrict__ hp) {
    __shared__ float lw[64][65];
    __shared__ float lh[16][65];
    int t = threadIdx.x;
    int rb = blockIdx.x * 16;
    for (int k = 0; k < 16; ++k) {
        int idx = t + k * 256;
        lw[idx >> 6][idx & 63] = Wp[idx];
    }
    for (int k = 0; k < 4; ++k) {
        int idx = t + k * 256;
        lh[idx >> 6][idx & 63] = h[rb * GDIM + idx];
    }
    __syncthreads();
    int o = t & 63, rg = t >> 6;
    float a0 = 0.f, a1 = 0.f, a2 = 0.f, a3 = 0.f;
    for (int c = 0; c < 64; ++c) {
        float wv = lw[o][c];
        a0 += lh[rg][c]      * wv;
        a1 += lh[rg + 4][c]  * wv;
        a2 += lh[rg + 8][c]  * wv;
        a3 += lh[rg + 12][c] * wv;
    }
    float bb = bpr[o];
    hp[(rb + rg) * GDIM + o]      = a0 + bb;
    hp[(rb + rg + 4) * GDIM + o]  = a1 + bb;
    hp[(rb + rg + 8) * GDIM + o]  = a2 + bb;
    hp[(rb + rg + 12) * GDIM + o] = a3 + bb;
}

// ---------------- K3a: dinv + gbf = bf16(g)  (one streaming pass over g) -------
// Same RNE rounding spmm used in-register, so results are bit-identical;
// dinv still computed from exact fp32 sums.
__global__ void rowsum_cvt(const float* __restrict__ g, unsigned short* __restrict__ gbf,
                           float* __restrict__ dinv) {
    int row = blockIdx.x, t = threadIdx.x;
    const f32x4* grow = (const f32x4*)(g + (size_t)row * GN);
    u16x4* brow = (u16x4*)(gbf + (size_t)row * GN);
    float s = 0.f;
    for (int k = 0; k < 16; ++k) {
        f32x4 v = grow[t + k * 256];
        s += (v[0] + v[1]) + (v[2] + v[3]);
        u16x4 u;
        u[0] = f2bf(v[0]); u[1] = f2bf(v[1]);
        u[2] = f2bf(v[2]); u[3] = f2bf(v[3]);
        brow[t + k * 256] = u;
    }
    for (int off = 32; off; off >>= 1) s += __shfl_down(s, off, 64);
    __shared__ float wsum[4];
    if ((t & 63) == 0) wsum[t >> 6] = s;
    __syncthreads();
    if (t == 0) {
        float tot = (wsum[0] + wsum[1]) + (wsum[2] + wsum[3]) + 1.0f;
        dinv[row] = rsqrtf(tot);
    }
}

// ---------------- K3b: dinv only (fallback when ws too small for gbf) ----------
__global__ void rowsum_dinv(const float* __restrict__ g, float* __restrict__ dinv) {
    int row = blockIdx.x, t = threadIdx.x;
    const f32x4* grow = (const f32x4*)(g + (size_t)row * GN);
    float s = 0.f;
    for (int k = 0; k < 16; ++k) {
        f32x4 v = grow[t + k * 256];
        s += (v[0] + v[1]) + (v[2] + v[3]);
    }
    for (int off = 32; off; off >>= 1) s += __shfl_down(s, off, 64);
    __shared__ float wsum[4];
    if ((t & 63) == 0) wsum[t >> 6] = s;
    __syncthreads();
    if (t == 0) {
        float tot = (wsum[0] + wsum[1]) + (wsum[2] + wsum[3]) + 1.0f;
        dinv[row] = rsqrtf(tot);
    }
}

// ---------------- K4: hsT[o][j] = bf16(dinv[j]*hp[j][o])  (transposed B) -------
__global__ void make_hsT(const float* __restrict__ hp, const float* __restrict__ dinv,
                         unsigned short* __restrict__ hsT) {
    __shared__ float tile[64][65];
    int t = threadIdx.x;
    int jb = blockIdx.x * 64;
    int o = t & 63, jg = t >> 6;
    for (int k = 0; k < 16; ++k) {
        int j = jg + k * 4;
        tile[j][o] = hp[(jb + j) * GDIM + o] * dinv[jb + j];
    }
    __syncthreads();
    int oo = t >> 2, q = t & 3;
    for (int k = 0; k < 16; ++k) {
        int j = q * 16 + k;
        hsT[(size_t)oo * GN + jb + j] = f2bf(tile[j][oo]);
    }
}

// ---------------- K5a: part[split] = gbf[i-tile,k-chunk] @ hsT[k-chunk,:] ------
// R5 structure exactly, A read as bf16 (16 B/lane/iter, no cvt chain).
// 256 blocks = 64 i-tiles (256 rows) x 4 k-splits; 16 waves (4/SIMD);
// wave owns 16 rows (1 m x 4 n). B staged in LDS 64x512 chunks, dbuf,
// chunk order rotated by itile.
__global__ void __launch_bounds__(1024, 4) spmm_bf(
    const unsigned short* __restrict__ gbf, const unsigned short* __restrict__ hsT,
    float* __restrict__ part)
{
    __shared__ unsigned short bs[2][64][520];   // 512 data + 8 pad shorts

    int t = threadIdx.x;
    int lane = t & 63;
    int w = t >> 6;                             // wave 0..15
    int itile = blockIdx.x >> 2;
    int split = blockIdx.x & 3;
    int rb = itile * 256;
    int kb = split * 4096;
    int l15 = lane & 15;
    int kg = lane >> 4;

    f32x4 acc[4];
    #pragma unroll
    for (int n = 0; n < 4; ++n)
        #pragma unroll
        for (int r = 0; r < 4; ++r) acc[n][r] = 0.f;

    const unsigned short* abase = gbf + (size_t)(rb + w * 16 + l15) * GN + kb + kg * 8;

    auto stage = [&](int kc, int buf) {
        int ck = kb + kc * 512;
        #pragma unroll
        for (int q = 0; q < 4; ++q) {
            int o = w * 4 + q;
            const char* src = (const char*)(hsT + (size_t)o * GN + ck) + lane * 16;
            __builtin_amdgcn_global_load_lds((GASV*)src, (LASV*)&bs[buf][o][0], 16, 0, 0);
        }
    };

    stage(itile & 7, 0);
    __syncthreads();

    for (int c = 0; c < 8; ++c) {
        int buf = c & 1;
        if (c < 7) stage((c + 1 + itile) & 7, buf ^ 1);

        int cbase = ((c + itile) & 7) * 512;
        for (int it = 0; it < 16; ++it) {
            int ko = it * 32 + kg * 8;
            bf16x8 bfr[4];
            #pragma unroll
            for (int n = 0; n < 4; ++n)
                bfr[n] = *(const bf16x8*)&bs[buf][n * 16 + l15][ko];
            bf16x8 afr = *(const bf16x8*)(abase + cbase + it * 32);
            #pragma unroll
            for (int n = 0; n < 4; ++n)
                acc[n] = __builtin_amdgcn_mfma_f32_16x16x32_bf16(afr, bfr[n], acc[n], 0, 0, 0);
        }
        __syncthreads();
    }

    float* pdst = part + (size_t)split * (GN * GDIM);
    #pragma unroll
    for (int n = 0; n < 4; ++n)
        #pragma unroll
        for (int r = 0; r < 4; ++r) {
            int i = rb + w * 16 + kg * 4 + r;   // C/D map: row=4*(lane>>4)+r
            int col = n * 16 + l15;             //          col=lane&15
            pdst[(size_t)i * GDIM + col] = acc[n][r];
        }
}

// ---------------- K5b: fallback spmm reading fp32 g (exact R5 kernel) ----------
__global__ void __launch_bounds__(1024, 4) spmm_part(
    const float* __restrict__ g, const unsigned short* __restrict__ hsT,
    float* __restrict__ part)
{
    __shared__ unsigned short bs[2][64][520];

    int t = threadIdx.x;
    int lane = t & 63;
    int w = t >> 6;
    int itile = blockIdx.x >> 2;
    int split = blockIdx.x & 3;
    int rb = itile * 256;
    int kb = split * 4096;
    int l15 = lane & 15;
    int kg = lane >> 4;

    f32x4 acc[4];
    #pragma unroll
    for (int n = 0; n < 4; ++n)
        #pragma unroll
        for (int r = 0; r < 4; ++r) acc[n][r] = 0.f;

    const float* abase = g + (size_t)(rb + w * 16 + l15) * GN + kb + kg * 8;

    auto stage = [&](int kc, int buf) {
        int ck = kb + kc * 512;
        #pragma unroll
        for (int q = 0; q < 4; ++q) {
            int o = w * 4 + q;
            const char* src = (const char*)(hsT + (size_t)o * GN + ck) + lane * 16;
            __builtin_amdgcn_global_load_lds((GASV*)src, (LASV*)&bs[buf][o][0], 16, 0, 0);
        }
    };

    stage(itile & 7, 0);
    __syncthreads();

    for (int c = 0; c < 8; ++c) {
        int buf = c & 1;
        if (c < 7) stage((c + 1 + itile) & 7, buf ^ 1);

        int cbase = ((c + itile) & 7) * 512;
        for (int it = 0; it < 16; ++it) {
            int ko = it * 32 + kg * 8;
            bf16x8 bfr[4];
            #pragma unroll
            for (int n = 0; n < 4; ++n)
                bfr[n] = *(const bf16x8*)&bs[buf][n * 16 + l15][ko];
            const float* ap = abase + cbase + it * 32;
            f32x4 x0 = *(const f32x4*)ap;
            f32x4 x1 = *((const f32x4*)ap + 1);
            bf16x8 afr;
            afr[0] = f2bf_hw(x0[0]); afr[1] = f2bf_hw(x0[1]);
            afr[2] = f2bf_hw(x0[2]); afr[3] = f2bf_hw(x0[3]);
            afr[4] = f2bf_hw(x1[0]); afr[5] = f2bf_hw(x1[1]);
            afr[6] = f2bf_hw(x1[2]); afr[7] = f2bf_hw(x1[3]);
            #pragma unroll
            for (int n = 0; n < 4; ++n)
                acc[n] = __builtin_amdgcn_mfma_f32_16x16x32_bf16(afr, bfr[n], acc[n], 0, 0, 0);
        }
        __syncthreads();
    }

    float* pdst = part + (size_t)split * (GN * GDIM);
    #pragma unroll
    for (int n = 0; n < 4; ++n)
        #pragma unroll
        for (int r = 0; r < 4; ++r) {
            int i = rb + w * 16 + kg * 4 + r;
            int col = n * 16 + l15;
            pdst[(size_t)i * GDIM + col] = acc[n][r];
        }
}

// ---------------- K6: out = leaky(dinv_i*(sum_s part + dinv_i*hp)) -------------
__global__ void epilogue(const float* __restrict__ part, const float* __restrict__ hp,
                         const float* __restrict__ dinv, float* __restrict__ out) {
    int q = blockIdx.x * 256 + threadIdx.x;   // 262144 quads = 16384 x 16
    int i = q >> 4;
    int o = (q & 15) * 4;
    size_t off = (size_t)i * GDIM + o;
    const size_t S = (size_t)GN * GDIM;
    f32x4 s0 = *(const f32x4*)(part + off);
    f32x4 s1 = *(const f32x4*)(part + S + off);
    f32x4 s2 = *(const f32x4*)(part + 2 * S + off);
    f32x4 s3 = *(const f32x4*)(part + 3 * S + off);
    f32x4 hpv = *(const f32x4*)(hp + off);
    float di = dinv[i];
    f32x4 v = (s0 + s1) + (s2 + s3);
    #pragma unroll
    for (int r = 0; r < 4; ++r) {
        float x = di * (v[r] + di * hpv[r]);
        v[r] = (x >= 0.f) ? x : 0.01f * x;
    }
    *(f32x4*)(out + off) = v;
}

extern "C" void kernel_launch(void* const* d_in, const int* in_sizes, int n_in,
                              void* d_out, int out_size, void* d_ws, size_t ws_size,
                              hipStream_t stream) {
    const float* g     = (const float*)d_in[0];
    const float* h     = (const float*)d_in[1];
    const float* W     = (const float*)d_in[2];
    const float* b     = (const float*)d_in[3];
    const float* gamma = (const float*)d_in[4];
    const float* beta  = (const float*)d_in[5];
    float* out = (float*)d_out;

    float* ws   = (float*)d_ws;
    float* ps   = ws;                        // 16384
    float* pq   = ws + 16384;                // 16384
    float* Wp   = ws + 32768;                // 4096
    float* bp   = ws + 36864;                // 64
    float* dinv = ws + 36928;                // 16384
    float* hp   = ws + 53312;                // 1048576 floats
    unsigned short* hsT = (unsigned short*)(ws + 1101888);   // 1 M shorts (2 MB)
    float* part = ws + 1626176;              // 4 x 1048576 floats (16 MB)
    unsigned short* gbf = (unsigned short*)(ws + 5820480);   // 256 M shorts (512 MB)
    const size_t WS_NEED = (size_t)(5820480 + 134217728) * 4;  // ~560.2 MB

    bn_partial  <<<256,   256, 0, stream>>>(h, ps, pq);
    bn_finalize <<<1,     256, 0, stream>>>(ps, pq, W, b, gamma, beta, Wp, bp);
    linear_hp   <<<1024,  256, 0, stream>>>(h, Wp, bp, hp);

    if (ws_size >= WS_NEED) {
        rowsum_cvt <<<16384, 256, 0, stream>>>(g, gbf, dinv);
        make_hsT   <<<256,   256, 0, stream>>>(hp, dinv, hsT);
        spmm_bf    <<<256,  1024, 0, stream>>>(gbf, hsT, part);
    } else {
        rowsum_dinv<<<16384, 256, 0, stream>>>(g, dinv);
        make_hsT   <<<256,   256, 0, stream>>>(hp, dinv, hsT);
        spmm_part  <<<256,  1024, 0, stream>>>(g, hsT, part);
    }
    epilogue    <<<1024,  256, 0, stream>>>(part, hp, dinv, out);
}

// Round 9
// 398.383 us; speedup vs baseline: 1.1321x; 1.1321x over previous
//
#include <hip/hip_runtime.h>
#include <hip/hip_bf16.h>

#define GN 16384
#define GDIM 64

typedef __attribute__((ext_vector_type(8))) short bf16x8;
typedef __attribute__((ext_vector_type(4))) float f32x4;

typedef __attribute__((address_space(1))) const void GASV;
typedef __attribute__((address_space(3))) void LASV;

__device__ __forceinline__ unsigned short f2bf(float x) {
    unsigned int u = __builtin_bit_cast(unsigned int, x);
    u += 0x7fffu + ((u >> 16) & 1u);          // round-to-nearest-even
    return (unsigned short)(u >> 16);
}

// compiler-visible float->bf16 cast; lowers to v_cvt_pk_bf16_f32 pairs (RNE)
__device__ __forceinline__ short f2bf_hw(float x) {
    __hip_bfloat16 b = __float2bfloat16(x);
    return (short)__builtin_bit_cast(unsigned short, b);
}

// ---------------- K1a: per-feature partial sums of h (256 blocks x 64 rows) ----
__global__ void bn_partial(const float* __restrict__ h, float* __restrict__ ps,
                           float* __restrict__ pq) {
    int b = blockIdx.x, t = threadIdx.x;
    int col = t & 63, wr = t >> 6;
    float s = 0.f, q = 0.f;
    int base = b * 64;
    for (int rep = 0; rep < 16; ++rep) {
        int row = base + wr + rep * 4;
        float v = h[row * GDIM + col];
        s += v; q += v * v;
    }
    __shared__ float ls[4][64], lq[4][64];
    ls[wr][col] = s; lq[wr][col] = q;
    __syncthreads();
    if (t < 64) {
        ps[b * 64 + t] = ls[0][t] + ls[1][t] + ls[2][t] + ls[3][t];
        pq[b * 64 + t] = lq[0][t] + lq[1][t] + lq[2][t] + lq[3][t];
    }
}

// ---------------- K1b: finalize BN stats, fold into W' and b' ------------------
__global__ void bn_finalize(const float* __restrict__ ps, const float* __restrict__ pq,
                            const float* __restrict__ W, const float* __restrict__ bvec,
                            const float* __restrict__ gamma, const float* __restrict__ beta,
                            float* __restrict__ Wp, float* __restrict__ bp) {
    int t = threadIdx.x;
    __shared__ float s_s[64], s_t2[64];
    if (t < 64) {
        float S = 0.f, Q = 0.f;
        for (int b = 0; b < 256; ++b) { S += ps[b * 64 + t]; Q += pq[b * 64 + t]; }
        float mean = S * (1.0f / 16384.0f);
        float var  = Q * (1.0f / 16384.0f) - mean * mean;
        float sc   = gamma[t] * rsqrtf(var + 1e-5f);
        s_s[t]  = sc;
        s_t2[t] = beta[t] - mean * sc;
    }
    __syncthreads();
    for (int k = 0; k < 16; ++k) {
        int idx = t + k * 256;
        Wp[idx] = s_s[idx & 63] * W[idx];
    }
    if (t < 64) {
        float acc = bvec[t];
        for (int c = 0; c < 64; ++c) acc += s_t2[c] * W[t * 64 + c];
        bp[t] = acc;
    }
}

// ---------------- K2: hp = h @ W'^T + b'   (1024 blocks x 16 rows) -------------
__global__ void linear_hp(const float* __restrict__ h, const float* __restrict__ Wp,
                          const float* __restrict__ bpr, float* __restrict__ hp) {
    __shared__ float lw[64][65];
    __shared__ float lh[16][65];
    int t = threadIdx.x;
    int rb = blockIdx.x * 16;
    for (int k = 0; k < 16; ++k) {
        int idx = t + k * 256;
        lw[idx >> 6][idx & 63] = Wp[idx];
    }
    for (int k = 0; k < 4; ++k) {
        int idx = t + k * 256;
        lh[idx >> 6][idx & 63] = h[rb * GDIM + idx];
    }
    __syncthreads();
    int o = t & 63, rg = t >> 6;
    float a0 = 0.f, a1 = 0.f, a2 = 0.f, a3 = 0.f;
    for (int c = 0; c < 64; ++c) {
        float wv = lw[o][c];
        a0 += lh[rg][c]      * wv;
        a1 += lh[rg + 4][c]  * wv;
        a2 += lh[rg + 8][c]  * wv;
        a3 += lh[rg + 12][c] * wv;
    }
    float bb = bpr[o];
    hp[(rb + rg) * GDIM + o]      = a0 + bb;
    hp[(rb + rg + 4) * GDIM + o]  = a1 + bb;
    hp[(rb + rg + 8) * GDIM + o]  = a2 + bb;
    hp[(rb + rg + 12) * GDIM + o] = a3 + bb;
}

// ---------------- K3: dinv[i] = rsqrt(1 + sum_j g[i,j])  (block per row) -------
__global__ void rowsum_dinv(const float* __restrict__ g, float* __restrict__ dinv) {
    int row = blockIdx.x, t = threadIdx.x;
    const f32x4* grow = (const f32x4*)(g + (size_t)row * GN);
    float s = 0.f;
    for (int k = 0; k < 16; ++k) {
        f32x4 v = grow[t + k * 256];
        s += (v[0] + v[1]) + (v[2] + v[3]);
    }
    for (int off = 32; off; off >>= 1) s += __shfl_down(s, off, 64);
    __shared__ float wsum[4];
    if ((t & 63) == 0) wsum[t >> 6] = s;
    __syncthreads();
    if (t == 0) {
        float tot = (wsum[0] + wsum[1]) + (wsum[2] + wsum[3]) + 1.0f;
        dinv[row] = rsqrtf(tot);
    }
}

// ---------------- K4: hsT[o][j] = bf16(dinv[j]*hp[j][o])  (transposed B) -------
__global__ void make_hsT(const float* __restrict__ hp, const float* __restrict__ dinv,
                         unsigned short* __restrict__ hsT) {
    __shared__ float tile[64][65];
    int t = threadIdx.x;
    int jb = blockIdx.x * 64;
    int o = t & 63, jg = t >> 6;
    for (int k = 0; k < 16; ++k) {
        int j = jg + k * 4;
        tile[j][o] = hp[(jb + j) * GDIM + o] * dinv[jb + j];
    }
    __syncthreads();
    int oo = t >> 2, q = t & 3;
    for (int k = 0; k < 16; ++k) {
        int j = q * 16 + k;
        hsT[(size_t)oo * GN + jb + j] = f2bf(tile[j][oo]);
    }
}

// ---------------- K5: partial[split] = g[i-tile, k-chunk] @ hsT[k-chunk, :] ----
// 256 blocks (= 1/CU) = 64 i-tiles (256 rows) x 4 k-splits (4096 k each).
// 1024 threads = 16 waves -> 4 waves/SIMD; wave owns 16 rows (1 m x 4 n).
// B staged in LDS 64x512-bf16 chunks via global_load_lds (1024 B rows, padded
// stride), double-buffered, one __syncthreads per chunk.
// Chunk visit order rotated by itile to spread instantaneous k-coverage
// across DRAM channels (A rows are 64 KB-strided; in-phase blocks would
// cluster on a channel subset).
__global__ void __launch_bounds__(1024, 4) spmm_part(
    const float* __restrict__ g, const unsigned short* __restrict__ hsT,
    float* __restrict__ part)
{
    __shared__ unsigned short bs[2][64][520];   // 512 data + 8 pad shorts

    int t = threadIdx.x;
    int lane = t & 63;
    int w = t >> 6;                             // wave 0..15
    int itile = blockIdx.x >> 2;
    int split = blockIdx.x & 3;
    int rb = itile * 256;
    int kb = split * 4096;
    int l15 = lane & 15;
    int kg = lane >> 4;

    f32x4 acc[4];
    #pragma unroll
    for (int n = 0; n < 4; ++n)
        #pragma unroll
        for (int r = 0; r < 4; ++r) acc[n][r] = 0.f;

    // A base: wave's 16 rows, lane's 32-float sub-window
    const float* abase = g + (size_t)(rb + w * 16 + l15) * GN + kb + kg * 8;

    // stage chunk kc (0..7 within split) into buffer buf: 64 rows x 512 bf16;
    // wave w stages rows w*4..w*4+3, one 1024 B global_load_lds per row.
    auto stage = [&](int kc, int buf) {
        int ck = kb + kc * 512;
        #pragma unroll
        for (int q = 0; q < 4; ++q) {
            int o = w * 4 + q;
            const char* src = (const char*)(hsT + (size_t)o * GN + ck) + lane * 16;
            __builtin_amdgcn_global_load_lds((GASV*)src, (LASV*)&bs[buf][o][0], 16, 0, 0);
        }
    };

    int c0 = blockIdx.x >> 2;                   // rotated chunk order (by itile)
    stage(c0 & 7, 0);
    __syncthreads();

    for (int c = 0; c < 8; ++c) {
        int buf = c & 1;
        if (c < 7) stage((c + 1 + c0) & 7, buf ^ 1);

        int cbase = ((c + c0) & 7) * 512;
        for (int it = 0; it < 16; ++it) {
            int ko = it * 32 + kg * 8;          // k-offset within chunk
            bf16x8 bfr[4];
            #pragma unroll
            for (int n = 0; n < 4; ++n)
                bfr[n] = *(const bf16x8*)&bs[buf][n * 16 + l15][ko];
            const float* ap = abase + cbase + it * 32;
            f32x4 x0 = *(const f32x4*)ap;
            f32x4 x1 = *((const f32x4*)ap + 1);
            bf16x8 afr;
            afr[0] = f2bf_hw(x0[0]); afr[1] = f2bf_hw(x0[1]);
            afr[2] = f2bf_hw(x0[2]); afr[3] = f2bf_hw(x0[3]);
            afr[4] = f2bf_hw(x1[0]); afr[5] = f2bf_hw(x1[1]);
            afr[6] = f2bf_hw(x1[2]); afr[7] = f2bf_hw(x1[3]);
            #pragma unroll
            for (int n = 0; n < 4; ++n)
                acc[n] = __builtin_amdgcn_mfma_f32_16x16x32_bf16(afr, bfr[n], acc[n], 0, 0, 0);
        }
        __syncthreads();                        // drains prefetch + LDS reuse
    }

    // direct store: wave owns its 16 rows
    float* pdst = part + (size_t)split * (GN * GDIM);
    #pragma unroll
    for (int n = 0; n < 4; ++n)
        #pragma unroll
        for (int r = 0; r < 4; ++r) {
            int i = rb + w * 16 + kg * 4 + r;   // C/D map: row=4*(lane>>4)+r
            int col = n * 16 + l15;             //          col=lane&15
            pdst[(size_t)i * GDIM + col] = acc[n][r];
        }
}

// ---------------- K6: out = leaky(dinv_i*(sum_s part + dinv_i*hp)) -------------
__global__ void epilogue(const float* __restrict__ part, const float* __restrict__ hp,
                         const float* __restrict__ dinv, float* __restrict__ out) {
    int q = blockIdx.x * 256 + threadIdx.x;   // 262144 quads = 16384 x 16
    int i = q >> 4;
    int o = (q & 15) * 4;
    size_t off = (size_t)i * GDIM + o;
    const size_t S = (size_t)GN * GDIM;
    f32x4 s0 = *(const f32x4*)(part + off);
    f32x4 s1 = *(const f32x4*)(part + S + off);
    f32x4 s2 = *(const f32x4*)(part + 2 * S + off);
    f32x4 s3 = *(const f32x4*)(part + 3 * S + off);
    f32x4 hpv = *(const f32x4*)(hp + off);
    float di = dinv[i];
    f32x4 v = (s0 + s1) + (s2 + s3);
    #pragma unroll
    for (int r = 0; r < 4; ++r) {
        float x = di * (v[r] + di * hpv[r]);
        v[r] = (x >= 0.f) ? x : 0.01f * x;
    }
    *(f32x4*)(out + off) = v;
}

extern "C" void kernel_launch(void* const* d_in, const int* in_sizes, int n_in,
                              void* d_out, int out_size, void* d_ws, size_t ws_size,
                              hipStream_t stream) {
    const float* g     = (const float*)d_in[0];
    const float* h     = (const float*)d_in[1];
    const float* W     = (const float*)d_in[2];
    const float* b     = (const float*)d_in[3];
    const float* gamma = (const float*)d_in[4];
    const float* beta  = (const float*)d_in[5];
    float* out = (float*)d_out;

    float* ws   = (float*)d_ws;
    float* ps   = ws;                        // 16384
    float* pq   = ws + 16384;                // 16384
    float* Wp   = ws + 32768;                // 4096
    float* bp   = ws + 36864;                // 64
    float* dinv = ws + 36928;                // 16384
    float* hp   = ws + 53312;                // 1048576 floats
    unsigned short* hsT = (unsigned short*)(ws + 1101888);  // 1 M shorts (2 MB)
    float* part = ws + 1626176;              // 4 x 1048576 floats = 16 MB

    bn_partial  <<<256,   256, 0, stream>>>(h, ps, pq);
    bn_finalize <<<1,     256, 0, stream>>>(ps, pq, W, b, gamma, beta, Wp, bp);
    linear_hp   <<<1024,  256, 0, stream>>>(h, Wp, bp, hp);
    rowsum_dinv <<<16384, 256, 0, stream>>>(g, dinv);
    make_hsT    <<<256,   256, 0, stream>>>(hp, dinv, hsT);
    spmm_part   <<<256,  1024, 0, stream>>>(g, hsT, part);
    epilogue    <<<1024,  256, 0, stream>>>(part, hp, dinv, out);
}